// Round 7
// baseline (237.895 us; speedup 1.0000x reference)
//
#include <hip/hip_runtime.h>
#include <hip/hip_bf16.h>

typedef __bf16 bf16_t;
typedef __bf16 bf16x4_t __attribute__((ext_vector_type(4)));
typedef __bf16 bf16x8_t __attribute__((ext_vector_type(8)));
typedef float f32x4_t __attribute__((ext_vector_type(4)));

#define NROWS 8192
#define DDIM  256
#define HDIM  512
#define CHUNK 128
#define NCHUNK (NROWS / CHUNK)   // 64

#define MFMA16(a, b, c) __builtin_amdgcn_mfma_f32_16x16x32_bf16((a), (b), (c), 0, 0, 0)
#define NEG_HALF_LOG2E -0.721347520444482f   // exp(-d2/2) = exp2(d2 * this)
// exp2f(d2 * NEG_HALF_LOG2E) == +0.0f for all d2 >= ~207.96. Flag with margin:
#define D2_FLAG 209.0f

// ---------------------------------------------------------------------------
// prep: X f32 -> Xb bf16, sq[i] = sum bf16(x)^2 (f32 accum). sq MUST use the
// bf16-rounded values so the diagonal d2 cancels exactly (K[i,i] = 1).
// Also zeroes the loss accumulators. (H needs no prep: phase 2 is rare and
// reads H f32 directly with the identical (bf16_t) conversion.)
// ---------------------------------------------------------------------------
__global__ __launch_bounds__(256) void prep_kernel(
    const float* __restrict__ x, bf16_t* __restrict__ xb,
    float* __restrict__ sq, float* __restrict__ partials)
{
    const int row  = (blockIdx.x << 2) + (threadIdx.x >> 6); // one wave per row
    const int lane = threadIdx.x & 63;
    float4 v = *reinterpret_cast<const float4*>(x + row * DDIM + (lane << 2));
    bf16x4_t b;
    b[0] = (bf16_t)v.x; b[1] = (bf16_t)v.y; b[2] = (bf16_t)v.z; b[3] = (bf16_t)v.w;
    *reinterpret_cast<bf16x4_t*>(xb + row * DDIM + (lane << 2)) = b;
    float f0 = (float)b[0], f1 = (float)b[1], f2 = (float)b[2], f3 = (float)b[3];
    float ss = f0 * f0 + f1 * f1 + f2 * f2 + f3 * f3;
    #pragma unroll
    for (int m = 32; m > 0; m >>= 1) ss += __shfl_xor(ss, m, 64);
    if (lane == 0) sq[row] = ss;
    if (blockIdx.x == 0 && threadIdx.x == 0) { partials[0] = 0.f; partials[1] = 0.f; }
}

// ---------------------------------------------------------------------------
// Main fused kernel. Grid = 256 blocks (32-row j-tile), 1024 thr = 16 waves
// (4 waves/SIMD; R5's 512 thr gave 2/SIMD and ~70% idle cycles). Wave w:
// isub = w&7 (16-row i-slice), par = w>>3 (scans even or odd chunks).
// NOTE: 16-wave blocks hard-cap VGPR at 128 -> phase 1 deliberately uses a
// SIMPLE load+scan loop (no explicit double buffer: that forces ~176 live
// regs -> scratch spills). Compiler pipelines within the budget; 4-wave TLP
// covers the rest.
//
// Phase 1 (barrier-free): per chunk compute S fragments (both m share the
//   B-frags -> half traffic) and flag iff any d2 < D2_FLAG, via one compare
//   S - (sqj-D2_FLAG)/2 > sqi/2. No exp: a SUPERSET mask is output-identical
//   because phase 2 recomputes P exactly (extra chunks contribute +0.0).
// Phase 2 (rare, waves 0-7): OR all 16 masks; per flagged chunk: recompute S,
//   P = exp2(-d2/2) -> swizzled LDS, barrier, O-GEMM (B gathered from H f32,
//   same (bf16_t) rounding as the old Hbt prep -> bit-identical), barrier.
// Epilogue: p1 = sum invlam*O^2, p2 = sum O*H -> LDS reduce -> 2 atomics.
// ---------------------------------------------------------------------------
__global__ __launch_bounds__(1024, 4) void kpca_main(
    const bf16_t* __restrict__ xb, const float* __restrict__ sq,
    const float* __restrict__ hmat, const float* __restrict__ invlam,
    float* __restrict__ partials)
{
    __shared__ bf16_t plds[32 * CHUNK];          // 8 KB
    __shared__ unsigned long long wmask[16];
    __shared__ float red[32];

    const int tid  = threadIdx.x;
    const int w    = tid >> 6;       // wave 0..15
    const int l    = tid & 63;
    const int l15  = l & 15;
    const int lq   = l >> 4;
    const int j0   = blockIdx.x << 5;
    const int isub = w & 7;          // i-slice within a 128-chunk
    const int par  = w >> 3;         // chunk parity scanned by this wave
    const int h0w  = (w & 7) << 6;   // phase-2 h-slice base

    // Hoisted A fragments, both m (loop-invariant): 64 VGPRs
    bf16x8_t av[2][8];
    #pragma unroll
    for (int m = 0; m < 2; ++m) {
        const bf16_t* aptr = xb + (size_t)(j0 + (m << 4) + l15) * DDIM + (lq << 3);
        #pragma unroll
        for (int kk = 0; kk < 8; ++kk)
            av[m][kk] = *reinterpret_cast<const bf16x8_t*>(aptr + (kk << 5));
    }
    float tj[2][4];
    #pragma unroll
    for (int m = 0; m < 2; ++m)
        #pragma unroll
        for (int r = 0; r < 4; ++r)
            tj[m][r] = (sq[j0 + (m << 4) + (lq << 2) + r] - D2_FLAG) * 0.5f;

    auto bptr_at = [&](int c) {
        return xb + (size_t)(c * CHUNK + (isub << 4) + l15) * DDIM + (lq << 3);
    };

    // scan: 16 MFMA, flag iff any (S - tj) > sqi/2  (<=> d2 < D2_FLAG)
    auto scan_chunk = [&](const bf16x8_t (&bv)[8], float ti) -> int {
        f32x4_t s[2][2];
        s[0][0] = s[0][1] = s[1][0] = s[1][1] = (f32x4_t){0.f, 0.f, 0.f, 0.f};
        #pragma unroll
        for (int kk = 0; kk < 8; kk += 2) {
            #pragma unroll
            for (int m = 0; m < 2; ++m) {
                s[m][0] = MFMA16(av[m][kk],     bv[kk],     s[m][0]);
                s[m][1] = MFMA16(av[m][kk + 1], bv[kk + 1], s[m][1]);
            }
        }
        float mx = -1e30f;
        #pragma unroll
        for (int m = 0; m < 2; ++m)
            #pragma unroll
            for (int r = 0; r < 4; ++r)
                mx = fmaxf(mx, (s[m][0][r] + s[m][1][r]) - tj[m][r]);
        return __any(mx > ti) ? 1 : 0;
    };

    // ---- phase 1: barrier-free parity scan (32 chunks per wave) ----
    unsigned long long mask = 0ull;
    #pragma unroll 2
    for (int t = 0; t < 32; ++t) {
        const int c = par + (t << 1);
        const bf16_t* pb = bptr_at(c);
        bf16x8_t bv[8];
        #pragma unroll
        for (int kk = 0; kk < 8; ++kk)
            bv[kk] = *reinterpret_cast<const bf16x8_t*>(pb + (kk << 5));
        const float ti = sq[c * CHUNK + (isub << 4) + l15] * 0.5f;
        if (scan_chunk(bv, ti)) mask |= (1ull << c);
    }

    wmask[w] = mask;
    __syncthreads();
    unsigned long long full = 0ull;
    #pragma unroll
    for (int i = 0; i < 16; ++i) full |= wmask[i];

    // ---- phase 2: flagged chunks (ascending ic; exact P path) ----
    f32x4_t acc[2][4];
    #pragma unroll
    for (int a = 0; a < 2; ++a)
        #pragma unroll
        for (int b = 0; b < 4; ++b)
            acc[a][b] = (f32x4_t){0.f, 0.f, 0.f, 0.f};

    while (full) {
        const int c = __ffsll(full) - 1;
        full &= full - 1ull;
        const int ic = c * CHUNK;

        if (w < 8) {
            bf16x8_t bv[8];
            const bf16_t* pb = bptr_at(c);
            #pragma unroll
            for (int kk = 0; kk < 8; ++kk)
                bv[kk] = *reinterpret_cast<const bf16x8_t*>(pb + (kk << 5));
            const float sqi = sq[ic + (isub << 4) + l15];
            f32x4_t s[2][2];
            s[0][0] = s[0][1] = s[1][0] = s[1][1] = (f32x4_t){0.f, 0.f, 0.f, 0.f};
            #pragma unroll
            for (int kk = 0; kk < 8; kk += 2) {
                #pragma unroll
                for (int m = 0; m < 2; ++m) {
                    s[m][0] = MFMA16(av[m][kk],     bv[kk],     s[m][0]);
                    s[m][1] = MFMA16(av[m][kk + 1], bv[kk + 1], s[m][1]);
                }
            }
            const int il = (isub << 4) + l15;
            const float sqj0 = tj[0][0] * 2.0f + D2_FLAG; // unused; keep simple:
            (void)sqj0;
            #pragma unroll
            for (int m = 0; m < 2; ++m)
                #pragma unroll
                for (int r = 0; r < 4; ++r) {
                    const float sqj = sq[j0 + (m << 4) + (lq << 2) + r];
                    float sv = s[m][0][r] + s[m][1][r];
                    float d2 = fmaxf(sqj + sqi - 2.0f * sv, 0.0f);
                    float p  = exp2f(d2 * NEG_HALF_LOG2E);
                    int jl = (m << 4) + (lq << 2) + r;
                    plds[(jl << 7) + (il ^ ((jl & 7) << 3))] = (bf16_t)p;
                }
        }
        __syncthreads();

        if (w < 8) {
            // O-GEMM: O[32j][64h slice] += P[32][128] @ H-slice (gathered f32)
            #pragma unroll
            for (int kf = 0; kf < 4; ++kf) {
                bf16x8_t pa[2];
                #pragma unroll
                for (int mf = 0; mf < 2; ++mf) {
                    int jl = (mf << 4) + l15;
                    int ik = (kf << 5) + (lq << 3);
                    pa[mf] = *reinterpret_cast<const bf16x8_t*>(
                        &plds[(jl << 7) + (ik ^ ((jl & 7) << 3))]);
                }
                #pragma unroll
                for (int nf = 0; nf < 4; ++nf) {
                    const float* hcol = hmat + (h0w + (nf << 4) + l15);
                    const int ib = ic + (kf << 5) + (lq << 3);
                    bf16x8_t hv;
                    #pragma unroll
                    for (int e = 0; e < 8; ++e)
                        hv[e] = (bf16_t)hcol[(size_t)(ib + e) * HDIM];
                    acc[0][nf] = MFMA16(pa[0], hv, acc[0][nf]);
                    acc[1][nf] = MFMA16(pa[1], hv, acc[1][nf]);
                }
            }
        }
        __syncthreads();   // protect plds before next flagged chunk
    }

    // ---- epilogue: loss partials (waves 0-7 hold all of O) ----
    float p1 = 0.f, p2 = 0.f;
    if (w < 8) {
        #pragma unroll
        for (int mf = 0; mf < 2; ++mf) {
            #pragma unroll
            for (int nf = 0; nf < 4; ++nf) {
                const int hh = h0w + (nf << 4) + l15;
                const float lam = invlam[hh];
                #pragma unroll
                for (int r = 0; r < 4; ++r) {
                    const int j = j0 + (mf << 4) + (lq << 2) + r;
                    const float v = acc[mf][nf][r];
                    p1 = fmaf(lam * v, v, p1);
                    p2 = fmaf(v, hmat[(size_t)j * HDIM + hh], p2);
                }
            }
        }
        #pragma unroll
        for (int sft = 32; sft > 0; sft >>= 1) {
            p1 += __shfl_xor(p1, sft, 64);
            p2 += __shfl_xor(p2, sft, 64);
        }
        if (l == 0) { red[w] = p1; red[16 + w] = p2; }
    }
    __syncthreads();
    if (tid == 0) {
        float a = 0.f, b = 0.f;
        #pragma unroll
        for (int i = 0; i < 8; ++i) { a += red[i]; b += red[16 + i]; }
        atomicAdd(&partials[0], a);
        atomicAdd(&partials[1], b);
    }
}

// ---------------------------------------------------------------------------
// finalize: s = loss1 + loss2, out = s + 0.05*s^2
// ---------------------------------------------------------------------------
__global__ void finalize_kernel(const float* __restrict__ partials,
                                float* __restrict__ out)
{
    if (threadIdx.x == 0) {
        float s = -0.5f * partials[0] + 0.5f * partials[1];
        out[0] = s + 0.05f * s * s;
    }
}

// ---------------------------------------------------------------------------
// ws layout: Xb bf16[8192][256] (4MB) | sq f32[8192] (32KB) | partials f32[2]
// ---------------------------------------------------------------------------
extern "C" void kernel_launch(void* const* d_in, const int* in_sizes, int n_in,
                              void* d_out, int out_size, void* d_ws, size_t ws_size,
                              hipStream_t stream)
{
    const float* x      = (const float*)d_in[0];
    const float* h      = (const float*)d_in[1];
    const float* invlam = (const float*)d_in[2];
    float* out = (float*)d_out;

    char* wsb = (char*)d_ws;
    bf16_t* xb  = (bf16_t*)wsb;
    float*  sq  = (float*)(wsb + (size_t)NROWS * DDIM * 2);
    float*  partials = sq + NROWS;

    hipLaunchKernelGGL(prep_kernel, dim3(NROWS / 4), dim3(256), 0, stream,
                       x, xb, sq, partials);
    hipLaunchKernelGGL(kpca_main, dim3(NROWS / 32), dim3(1024), 0, stream,
                       xb, sq, h, invlam, partials);
    hipLaunchKernelGGL(finalize_kernel, dim3(1), dim3(64), 0, stream,
                       partials, out);
}

// Round 9
// 216.598 us; speedup vs baseline: 1.0983x; 1.0983x over previous
//
#include <hip/hip_runtime.h>
#include <hip/hip_bf16.h>

typedef __bf16 bf16_t;
typedef __bf16 bf16x4_t __attribute__((ext_vector_type(4)));
typedef __bf16 bf16x8_t __attribute__((ext_vector_type(8)));
typedef float f32x4_t __attribute__((ext_vector_type(4)));

#define NROWS 8192
#define DDIM  256
#define HDIM  512
#define CHUNK 128
#define NCHUNK (NROWS / CHUNK)   // 64

#define MFMA16(a, b, c) __builtin_amdgcn_mfma_f32_16x16x32_bf16((a), (b), (c), 0, 0, 0)
#define NEG_HALF_LOG2E -0.721347520444482f   // exp(-d2/2) = exp2(d2 * this)
// exp2f(d2 * NEG_HALF_LOG2E) == +0.0f for all d2 >= ~207.96. Flag with margin:
#define D2_FLAG 209.0f

// ---------------------------------------------------------------------------
// prep: X f32 -> Xb bf16, sq[i] = sum bf16(x)^2 (f32 accum). sq MUST use the
// bf16-rounded values so the diagonal d2 cancels exactly (K[i,i] = 1).
// Also zeroes the loss accumulators.
// ---------------------------------------------------------------------------
__global__ __launch_bounds__(256) void prep_kernel(
    const float* __restrict__ x, bf16_t* __restrict__ xb,
    float* __restrict__ sq, float* __restrict__ partials)
{
    const int row  = (blockIdx.x << 2) + (threadIdx.x >> 6); // one wave per row
    const int lane = threadIdx.x & 63;
    float4 v = *reinterpret_cast<const float4*>(x + row * DDIM + (lane << 2));
    bf16x4_t b;
    b[0] = (bf16_t)v.x; b[1] = (bf16_t)v.y; b[2] = (bf16_t)v.z; b[3] = (bf16_t)v.w;
    *reinterpret_cast<bf16x4_t*>(xb + row * DDIM + (lane << 2)) = b;
    float f0 = (float)b[0], f1 = (float)b[1], f2 = (float)b[2], f3 = (float)b[3];
    float ss = f0 * f0 + f1 * f1 + f2 * f2 + f3 * f3;
    #pragma unroll
    for (int m = 32; m > 0; m >>= 1) ss += __shfl_xor(ss, m, 64);
    if (lane == 0) sq[row] = ss;
    if (blockIdx.x == 0 && threadIdx.x == 0) { partials[0] = 0.f; partials[1] = 0.f; }
}

// ---------------------------------------------------------------------------
// scan_kernel (hot path): grid = 512 blocks = (jtile 0..255) x (parity half).
// 512 thr = 8 waves, __launch_bounds__(512,4) -> VGPR cap 128, 2 blocks/CU
// = 4 waves/SIMD (R5 ran 2/SIMD and was latency-bound; R7's 16-wave variant
// spilled: 157 MB scratch traffic at VGPR_Count=64). The scan carries no
// O-accumulator, so the live set fits the cap: av 64 + bv 32 + s 8 + tj 8
// + scalars ~ 120. Deliberately NO unroll pragma (would keep 2 bv sets live
// -> spill) and single MFMA chain per m (2 chains total; TLP hides latency).
// Each block scans the 32 chunks c === half (mod 2) for its 32-row j-tile:
// flag iff any d2 < D2_FLAG via the exp-free compare
//   S - (sqj - D2_FLAG)/2 > sqi/2.
// Superset mask is safe: solve_kernel recomputes P exactly; extra chunks
// contribute exactly +0.0. Writes maskpart[blockIdx.x] unconditionally.
// ---------------------------------------------------------------------------
__global__ __launch_bounds__(512, 4) void scan_kernel(
    const bf16_t* __restrict__ xb, const float* __restrict__ sq,
    unsigned long long* __restrict__ maskpart)
{
    __shared__ unsigned long long wmask[8];

    const int tid  = threadIdx.x;
    const int w    = tid >> 6;       // wave 0..7 = i-slice
    const int l    = tid & 63;
    const int l15  = l & 15;
    const int lq   = l >> 4;
    const int jt   = blockIdx.x >> 1;
    const int half = blockIdx.x & 1; // chunk parity this block scans
    const int j0   = jt << 5;
    const int isub = w;

    // Hoisted A fragments, both m (loop-invariant): 64 VGPRs
    bf16x8_t av[2][8];
    #pragma unroll
    for (int m = 0; m < 2; ++m) {
        const bf16_t* aptr = xb + (size_t)(j0 + (m << 4) + l15) * DDIM + (lq << 3);
        #pragma unroll
        for (int kk = 0; kk < 8; ++kk)
            av[m][kk] = *reinterpret_cast<const bf16x8_t*>(aptr + (kk << 5));
    }
    float tj[2][4];
    #pragma unroll
    for (int m = 0; m < 2; ++m)
        #pragma unroll
        for (int r = 0; r < 4; ++r)
            tj[m][r] = (sq[j0 + (m << 4) + (lq << 2) + r] - D2_FLAG) * 0.5f;

    unsigned long long mask = 0ull;
    for (int t = 0; t < 32; ++t) {
        const int c = half + (t << 1);
        const bf16_t* pb =
            xb + (size_t)(c * CHUNK + (isub << 4) + l15) * DDIM + (lq << 3);
        bf16x8_t bv[8];
        #pragma unroll
        for (int kk = 0; kk < 8; ++kk)
            bv[kk] = *reinterpret_cast<const bf16x8_t*>(pb + (kk << 5));
        const float ti = sq[c * CHUNK + (isub << 4) + l15] * 0.5f;

        // single accumulator chain per m -> 2 independent chains, 8 VGPRs
        f32x4_t s[2];
        s[0] = s[1] = (f32x4_t){0.f, 0.f, 0.f, 0.f};
        #pragma unroll
        for (int kk = 0; kk < 8; ++kk) {
            s[0] = MFMA16(av[0][kk], bv[kk], s[0]);
            s[1] = MFMA16(av[1][kk], bv[kk], s[1]);
        }
        float mx = -1e30f;
        #pragma unroll
        for (int m = 0; m < 2; ++m)
            #pragma unroll
            for (int r = 0; r < 4; ++r)
                mx = fmaxf(mx, s[m][r] - tj[m][r]);
        if (__any(mx > ti)) mask |= (1ull << c);
    }

    if (l == 0) wmask[w] = mask;
    __syncthreads();
    if (tid == 0) {
        unsigned long long m2 = 0ull;
        #pragma unroll
        for (int i = 0; i < 8; ++i) m2 |= wmask[i];
        maskpart[blockIdx.x] = m2;
    }
}

// ---------------------------------------------------------------------------
// solve_kernel (rare path): grid = 256 (one per j-tile), 512 thr = 8 waves,
// full 256-VGPR budget. For each flagged chunk (ascending): recompute S
// exactly, P = exp2(-d2/2) -> swizzled LDS, barrier, O-GEMM (B-frags gathered
// from H f32 with the same (bf16_t) rounding -- path validated in R7), barrier.
// Epilogue: p1 = sum invlam*O^2, p2 = sum O*H -> LDS reduce -> 2 atomics.
// ---------------------------------------------------------------------------
__global__ __launch_bounds__(512, 2) void solve_kernel(
    const bf16_t* __restrict__ xb, const float* __restrict__ sq,
    const float* __restrict__ hmat, const float* __restrict__ invlam,
    const unsigned long long* __restrict__ maskpart,
    float* __restrict__ partials)
{
    __shared__ bf16_t plds[32 * CHUNK];          // 8 KB
    __shared__ float red[32];

    const int tid  = threadIdx.x;
    const int w    = tid >> 6;       // wave 0..7
    const int l    = tid & 63;
    const int l15  = l & 15;
    const int lq   = l >> 4;
    const int jt   = blockIdx.x;
    const int j0   = jt << 5;
    const int isub = w;              // i-slice within a 128-chunk
    const int h0w  = w << 6;         // h-slice base

    unsigned long long full = maskpart[jt << 1] | maskpart[(jt << 1) + 1];

    // Hoisted A fragments, both m
    bf16x8_t av[2][8];
    #pragma unroll
    for (int m = 0; m < 2; ++m) {
        const bf16_t* aptr = xb + (size_t)(j0 + (m << 4) + l15) * DDIM + (lq << 3);
        #pragma unroll
        for (int kk = 0; kk < 8; ++kk)
            av[m][kk] = *reinterpret_cast<const bf16x8_t*>(aptr + (kk << 5));
    }
    float sqj[2][4];
    #pragma unroll
    for (int m = 0; m < 2; ++m)
        #pragma unroll
        for (int r = 0; r < 4; ++r)
            sqj[m][r] = sq[j0 + (m << 4) + (lq << 2) + r];

    f32x4_t acc[2][4];
    #pragma unroll
    for (int a = 0; a < 2; ++a)
        #pragma unroll
        for (int b = 0; b < 4; ++b)
            acc[a][b] = (f32x4_t){0.f, 0.f, 0.f, 0.f};

    while (full) {
        const int c = __ffsll(full) - 1;
        full &= full - 1ull;
        const int ic = c * CHUNK;

        bf16x8_t bv[8];
        const bf16_t* pb =
            xb + (size_t)(ic + (isub << 4) + l15) * DDIM + (lq << 3);
        #pragma unroll
        for (int kk = 0; kk < 8; ++kk)
            bv[kk] = *reinterpret_cast<const bf16x8_t*>(pb + (kk << 5));
        const float sqi = sq[ic + (isub << 4) + l15];
        f32x4_t s[2][2];
        s[0][0] = s[0][1] = s[1][0] = s[1][1] = (f32x4_t){0.f, 0.f, 0.f, 0.f};
        #pragma unroll
        for (int kk = 0; kk < 8; kk += 2) {
            #pragma unroll
            for (int m = 0; m < 2; ++m) {
                s[m][0] = MFMA16(av[m][kk],     bv[kk],     s[m][0]);
                s[m][1] = MFMA16(av[m][kk + 1], bv[kk + 1], s[m][1]);
            }
        }
        const int il = (isub << 4) + l15;
        #pragma unroll
        for (int m = 0; m < 2; ++m)
            #pragma unroll
            for (int r = 0; r < 4; ++r) {
                float sv = s[m][0][r] + s[m][1][r];
                float d2 = fmaxf(sqj[m][r] + sqi - 2.0f * sv, 0.0f);
                float p  = exp2f(d2 * NEG_HALF_LOG2E);
                int jl = (m << 4) + (lq << 2) + r;
                plds[(jl << 7) + (il ^ ((jl & 7) << 3))] = (bf16_t)p;
            }
        __syncthreads();

        // O-GEMM: O[32j][64h slice] += P[32][128] @ H-slice (gathered f32)
        #pragma unroll
        for (int kf = 0; kf < 4; ++kf) {
            bf16x8_t pa[2];
            #pragma unroll
            for (int mf = 0; mf < 2; ++mf) {
                int jl = (mf << 4) + l15;
                int ik = (kf << 5) + (lq << 3);
                pa[mf] = *reinterpret_cast<const bf16x8_t*>(
                    &plds[(jl << 7) + (ik ^ ((jl & 7) << 3))]);
            }
            #pragma unroll
            for (int nf = 0; nf < 4; ++nf) {
                const float* hcol = hmat + (h0w + (nf << 4) + l15);
                const int ib = ic + (kf << 5) + (lq << 3);
                bf16x8_t hv;
                #pragma unroll
                for (int e = 0; e < 8; ++e)
                    hv[e] = (bf16_t)hcol[(size_t)(ib + e) * HDIM];
                acc[0][nf] = MFMA16(pa[0], hv, acc[0][nf]);
                acc[1][nf] = MFMA16(pa[1], hv, acc[1][nf]);
            }
        }
        __syncthreads();   // protect plds before next flagged chunk
    }

    // ---- epilogue: loss partials ----
    float p1 = 0.f, p2 = 0.f;
    #pragma unroll
    for (int mf = 0; mf < 2; ++mf) {
        #pragma unroll
        for (int nf = 0; nf < 4; ++nf) {
            const int hh = h0w + (nf << 4) + l15;
            const float lam = invlam[hh];
            #pragma unroll
            for (int r = 0; r < 4; ++r) {
                const int j = j0 + (mf << 4) + (lq << 2) + r;
                const float v = acc[mf][nf][r];
                p1 = fmaf(lam * v, v, p1);
                p2 = fmaf(v, hmat[(size_t)j * HDIM + hh], p2);
            }
        }
    }
    #pragma unroll
    for (int sft = 32; sft > 0; sft >>= 1) {
        p1 += __shfl_xor(p1, sft, 64);
        p2 += __shfl_xor(p2, sft, 64);
    }
    if (l == 0) { red[w] = p1; red[16 + w] = p2; }
    __syncthreads();
    if (tid == 0) {
        float a = 0.f, b = 0.f;
        #pragma unroll
        for (int i = 0; i < 8; ++i) { a += red[i]; b += red[16 + i]; }
        atomicAdd(&partials[0], a);
        atomicAdd(&partials[1], b);
    }
}

// ---------------------------------------------------------------------------
// finalize: s = loss1 + loss2, out = s + 0.05*s^2
// ---------------------------------------------------------------------------
__global__ void finalize_kernel(const float* __restrict__ partials,
                                float* __restrict__ out)
{
    if (threadIdx.x == 0) {
        float s = -0.5f * partials[0] + 0.5f * partials[1];
        out[0] = s + 0.05f * s * s;
    }
}

// ---------------------------------------------------------------------------
// ws layout: Xb bf16[8192][256] (4MB) | sq f32[8192] (32KB) | partials f32[2]
//            | pad | maskpart u64[512] (4KB)
// ---------------------------------------------------------------------------
extern "C" void kernel_launch(void* const* d_in, const int* in_sizes, int n_in,
                              void* d_out, int out_size, void* d_ws, size_t ws_size,
                              hipStream_t stream)
{
    const float* x      = (const float*)d_in[0];
    const float* h      = (const float*)d_in[1];
    const float* invlam = (const float*)d_in[2];
    float* out = (float*)d_out;

    char* wsb = (char*)d_ws;
    bf16_t* xb  = (bf16_t*)wsb;
    float*  sq  = (float*)(wsb + (size_t)NROWS * DDIM * 2);
    float*  partials = sq + NROWS;
    unsigned long long* maskpart =
        (unsigned long long*)(wsb + (size_t)NROWS * DDIM * 2 + 64 * 1024);

    hipLaunchKernelGGL(prep_kernel, dim3(NROWS / 4), dim3(256), 0, stream,
                       x, xb, sq, partials);
    hipLaunchKernelGGL(scan_kernel, dim3(512), dim3(512), 0, stream,
                       xb, sq, maskpart);
    hipLaunchKernelGGL(solve_kernel, dim3(NROWS / 32), dim3(512), 0, stream,
                       xb, sq, h, invlam, maskpart, partials);
    hipLaunchKernelGGL(finalize_kernel, dim3(1), dim3(64), 0, stream,
                       partials, out);
}